// Round 1
// baseline (107.000 us; speedup 1.0000x reference)
//
#include <hip/hip_runtime.h>

#define B_SZ 4096
#define D_SZ 1024
#define NB 32
#define DF 64      // features per eval tile
#define RB 64      // rows per eval tile
#define STRIDE 33  // LDS leading-dim pad: bank = (f+k)%32, 2-way = free

constexpr float MBW = 0.001f;
constexpr float MBH = 0.001f;

// ---------------------------------------------------------------------------
// Kernel A: per-feature spline parameters. 256 thr = 8 features x 32 bins.
// Writes gCoef[f*32+k] = (a, b, c, d) and gEdge[f*32+k] = (search_edge, left_cw).
// Also zeroes the logabsdet accumulator region of d_out.
// ---------------------------------------------------------------------------
__global__ __launch_bounds__(256) void spline_params(
    const float* __restrict__ uw, const float* __restrict__ uh,
    const float* __restrict__ udl, const float* __restrict__ udr,
    float4* __restrict__ gCoef, float2* __restrict__ gEdge,
    float* __restrict__ lad_out)
{
    const int tid = threadIdx.x;
    const int gidx = blockIdx.x * 256 + tid;
    if (gidx < B_SZ) lad_out[gidx] = 0.0f;   // zero before eval kernel's atomics

    const int f = blockIdx.x * 8 + (tid >> 5);
    const int k = tid & 31;

    const float w_raw = uw[f * NB + k];
    const float h_raw = uh[f * NB + k];

    // softmax(widths) within the 32-lane segment (masks <=16 stay in-segment)
    float m = w_raw;
    for (int mm = 16; mm >= 1; mm >>= 1) m = fmaxf(m, __shfl_xor(m, mm));
    const float e = expf(w_raw - m);
    float sum = e;
    for (int mm = 16; mm >= 1; mm >>= 1) sum += __shfl_xor(sum, mm);
    const float w = MBW + (1.0f - MBW * NB) * (e / sum);

    // softmax(heights)
    float mh = h_raw;
    for (int mm = 16; mm >= 1; mm >>= 1) mh = fmaxf(mh, __shfl_xor(mh, mm));
    const float eh = expf(h_raw - mh);
    float sumh = eh;
    for (int mm = 16; mm >= 1; mm >>= 1) sumh += __shfl_xor(sumh, mm);
    const float h = MBH + (1.0f - MBH * NB) * (eh / sumh);

    const float slope = h / w;

    // inclusive scans (cumsum) over the 32-lane segment
    float cw = w, ch = h;
    for (int off = 1; off < 32; off <<= 1) {
        float t1 = __shfl_up(cw, off, 32);
        float t2 = __shfl_up(ch, off, 32);
        if (k >= off) { cw += t1; ch += t2; }
    }
    // exclusive (left) edges — exact same values as ref's padded cumsum
    float cwl = __shfl_up(cw, 1, 32); if (k == 0) cwl = 0.0f;
    float chl = __shfl_up(ch, 1, 32); if (k == 0) chl = 0.0f;
    // search array: Ls[j]=cumsum_w[j] for j<31; sentinel > any input at j=31
    const float Ls = (k == 31) ? 2.0f : cw;

    // monotone derivatives
    const float slope_n = __shfl_down(slope, 1, 32);
    const float w_n     = __shfl_down(w, 1, 32);
    const float min1 = fminf(fabsf(slope), fabsf(slope_n));
    const float min2 = 0.5f * (w_n * slope + w * slope_n) / (w + w_n);
    const float sg  = (slope   > 0.f ? 1.f : 0.f) - (slope   < 0.f ? 1.f : 0.f);
    const float sgn = (slope_n > 0.f ? 1.f : 0.f) - (slope_n < 0.f ? 1.f : 0.f);
    const float inner = fminf(min1, min2) * (sg + sgn);   // derivatives[k+1], valid k<=30

    float d_right;
    if (k == 31) {
        const float x = udr[f];
        d_right = (1.0f / (1.0f + expf(-x))) * 3.0f * slope;
    } else {
        d_right = inner;
    }
    const float inner_prev = __shfl_up(inner, 1, 32);
    float d_left;
    if (k == 0) {
        const float x = udl[f];
        d_left = (1.0f / (1.0f + expf(-x))) * 3.0f * slope;
    } else {
        d_left = inner_prev;
    }

    const float a = (d_left + d_right - 2.0f * slope) / (w * w);
    const float b = (3.0f * slope - 2.0f * d_left - d_right) / w;

    gCoef[f * NB + k] = make_float4(a, b, d_left, chl);
    gEdge[f * NB + k] = make_float2(Ls, cwl);
}

// ---------------------------------------------------------------------------
// Kernel B: evaluate 4M elements. Block tile = DF features x RB rows.
// Tables staged in LDS (stride-33 pad); branchless binary search; each wave
// covers one full row-slice -> shuffle-reduce logabsdet + 1 atomic/wave-iter.
// ---------------------------------------------------------------------------
__global__ __launch_bounds__(256) void spline_eval(
    const float* __restrict__ inp,
    const float4* __restrict__ gCoef,
    const float2* __restrict__ gEdge,
    float* __restrict__ out, float* __restrict__ lad)
{
    __shared__ float sLs [DF * STRIDE];
    __shared__ float sCWL[DF * STRIDE];
    __shared__ float sA  [DF * STRIDE];
    __shared__ float sB  [DF * STRIDE];
    __shared__ float sC  [DF * STRIDE];
    __shared__ float sD  [DF * STRIDE];

    const int tid = threadIdx.x;
    const int ft = blockIdx.x % (D_SZ / DF);
    const int rt = blockIdx.x / (D_SZ / DF);
    const int f0 = ft * DF;
    const int r0 = rt * RB;

    // stage tables (coalesced float4/float2 loads -> conflict-free LDS writes)
    for (int t = tid; t < DF * NB; t += 256) {
        const int fl = t >> 5, kk = t & 31;
        const float4 cf = gCoef[(f0 + fl) * NB + kk];
        const float2 ed = gEdge[(f0 + fl) * NB + kk];
        sA [fl * STRIDE + kk] = cf.x;
        sB [fl * STRIDE + kk] = cf.y;
        sC [fl * STRIDE + kk] = cf.z;
        sD [fl * STRIDE + kk] = cf.w;
        sLs[fl * STRIDE + kk] = ed.x;
        sCWL[fl * STRIDE + kk] = ed.y;
    }
    __syncthreads();

    const int fl = tid & 63;         // lane -> feature within tile
    const int rowoff = tid >> 6;     // wave -> row within group of 4
    const float* Lbase = &sLs[fl * STRIDE];

    for (int it = 0; it < RB / 4; ++it) {
        const int r = r0 + it * 4 + rowoff;
        const float x = inp[r * D_SZ + f0 + fl];

        // branchless binary search: pos = #{j in 0..31 : x >= Ls[j]} in [0,31]
        int pos = 0;
        if (x >= Lbase[pos + 15]) pos += 16;
        if (x >= Lbase[pos + 7])  pos += 8;
        if (x >= Lbase[pos + 3])  pos += 4;
        if (x >= Lbase[pos + 1])  pos += 2;
        if (x >= Lbase[pos])      pos += 1;

        const int idx = fl * STRIDE + pos;
        const float a = sA[idx], b = sB[idx], c = sC[idx], d = sD[idx];
        const float s = x - sCWL[idx];

        float o = ((a * s + b) * s + c) * s + d;
        o = fminf(fmaxf(o, 0.0f), 1.0f);
        out[r * D_SZ + f0 + fl] = o;

        const float der = (3.0f * a * s + 2.0f * b) * s + c;
        float l = logf(fabsf(der));
        // full-wave reduce: each wave's 64 lanes = one row-slice of 64 features
        for (int mm = 32; mm >= 1; mm >>= 1) l += __shfl_xor(l, mm);
        if ((tid & 63) == 0) atomicAdd(&lad[r], l);
    }
}

// ---------------------------------------------------------------------------
extern "C" void kernel_launch(void* const* d_in, const int* in_sizes, int n_in,
                              void* d_out, int out_size, void* d_ws, size_t ws_size,
                              hipStream_t stream)
{
    const float* inputs = (const float*)d_in[0];
    const float* uw     = (const float*)d_in[1];
    const float* uh     = (const float*)d_in[2];
    const float* udl    = (const float*)d_in[3];
    const float* udr    = (const float*)d_in[4];

    float* out = (float*)d_out;                        // B*D outputs
    float* lad = out + (size_t)B_SZ * D_SZ;            // B logabsdet sums

    float4* gCoef = (float4*)d_ws;                                       // D*32 * 16B
    float2* gEdge = (float2*)((char*)d_ws + (size_t)D_SZ * NB * sizeof(float4));

    spline_params<<<D_SZ / 8, 256, 0, stream>>>(uw, uh, udl, udr, gCoef, gEdge, lad);
    spline_eval<<<(D_SZ / DF) * (B_SZ / RB), 256, 0, stream>>>(inputs, gCoef, gEdge, out, lad);
}

// Round 2
// 84.864 us; speedup vs baseline: 1.2608x; 1.2608x over previous
//
#include <hip/hip_runtime.h>

#define B_SZ 4096
#define D_SZ 1024
#define NB 32
#define DF 64       // features per eval tile
#define RB 128      // rows per eval tile
// LDS strides (in element units noted per array) chosen for 16B alignment of
// float4 reads + non-pathological bank groups: 4*(fl+idx)%32 -> 8 groups of 4.
#define LSQ_STRIDE 9    // sLs:    9 float4 = 36 floats per feature
#define CO_STRIDE  33   // sCoef: 33 float4 per feature
#define CR_STRIDE  3    // sCoarse: 3 float4 = 12 floats per feature

constexpr float MBW = 0.001f;
constexpr float MBH = 0.001f;

// ---------------------------------------------------------------------------
// Kernel A: per-feature spline parameters. 256 thr = 8 features x 32 bins.
// gCoef[f*32+k] = (a, b, c=d_left, d=chl);  gLs[f*32+k] = search edge
// (cumw[k], sentinel 2.0 at k=31). Also zeroes the logabsdet accumulators.
// ---------------------------------------------------------------------------
__global__ __launch_bounds__(256) void spline_params(
    const float* __restrict__ uw, const float* __restrict__ uh,
    const float* __restrict__ udl, const float* __restrict__ udr,
    float4* __restrict__ gCoef, float* __restrict__ gLs,
    float* __restrict__ lad_out)
{
    const int tid = threadIdx.x;
    const int gidx = blockIdx.x * 256 + tid;
    if (gidx < B_SZ) lad_out[gidx] = 0.0f;   // zero before eval kernel's atomics

    const int f = blockIdx.x * 8 + (tid >> 5);
    const int k = tid & 31;

    const float w_raw = uw[f * NB + k];
    const float h_raw = uh[f * NB + k];

    // softmax(widths) within the 32-lane segment
    float m = w_raw;
    for (int mm = 16; mm >= 1; mm >>= 1) m = fmaxf(m, __shfl_xor(m, mm));
    const float e = __expf(w_raw - m);
    float sum = e;
    for (int mm = 16; mm >= 1; mm >>= 1) sum += __shfl_xor(sum, mm);
    const float w = MBW + (1.0f - MBW * NB) * (e / sum);

    // softmax(heights)
    float mh = h_raw;
    for (int mm = 16; mm >= 1; mm >>= 1) mh = fmaxf(mh, __shfl_xor(mh, mm));
    const float eh = __expf(h_raw - mh);
    float sumh = eh;
    for (int mm = 16; mm >= 1; mm >>= 1) sumh += __shfl_xor(sumh, mm);
    const float h = MBH + (1.0f - MBH * NB) * (eh / sumh);

    const float slope = h / w;

    // inclusive scans (cumsum) over the 32-lane segment
    float cw = w, ch = h;
    for (int off = 1; off < 32; off <<= 1) {
        float t1 = __shfl_up(cw, off, 32);
        float t2 = __shfl_up(ch, off, 32);
        if (k >= off) { cw += t1; ch += t2; }
    }
    float chl = __shfl_up(ch, 1, 32); if (k == 0) chl = 0.0f;   // d = left cumheight
    const float Ls = (k == 31) ? 2.0f : cw;                     // sentinel > any x

    // monotone derivatives
    const float slope_n = __shfl_down(slope, 1, 32);
    const float w_n     = __shfl_down(w, 1, 32);
    const float min1 = fminf(fabsf(slope), fabsf(slope_n));
    const float min2 = 0.5f * (w_n * slope + w * slope_n) / (w + w_n);
    const float sg  = (slope   > 0.f ? 1.f : 0.f) - (slope   < 0.f ? 1.f : 0.f);
    const float sgn = (slope_n > 0.f ? 1.f : 0.f) - (slope_n < 0.f ? 1.f : 0.f);
    const float inner = fminf(min1, min2) * (sg + sgn);   // derivatives[k+1]

    float d_right;
    if (k == 31) {
        const float x = udr[f];
        d_right = (1.0f / (1.0f + __expf(-x))) * 3.0f * slope;
    } else {
        d_right = inner;
    }
    const float inner_prev = __shfl_up(inner, 1, 32);
    float d_left;
    if (k == 0) {
        const float x = udl[f];
        d_left = (1.0f / (1.0f + __expf(-x))) * 3.0f * slope;
    } else {
        d_left = inner_prev;
    }

    const float a = (d_left + d_right - 2.0f * slope) / (w * w);
    const float b = (3.0f * slope - 2.0f * d_left - d_right) / w;

    gCoef[f * NB + k] = make_float4(a, b, d_left, chl);
    gLs[f * NB + k] = Ls;
}

// ---------------------------------------------------------------------------
// Kernel B: evaluate 4M elements. Block = 512 thr (8 waves), tile = 64 feat
// x 128 rows. Lane handles 4 consecutive features (dwordx4 in/out); 16 lanes
// cover a row; wave covers 4 rows/iter. Search: register-resident coarse
// octant (8 cmp) -> 1 ds_read_b128 fine quad -> 1 ds_read_b128 coef.
// ---------------------------------------------------------------------------
__global__ __launch_bounds__(512) void spline_eval(
    const float4* __restrict__ inp,
    const float4* __restrict__ gCoef,
    const float* __restrict__ gLs,
    float4* __restrict__ out, float* __restrict__ lad)
{
    __shared__ float4 sLsQ   [DF * LSQ_STRIDE];  // fine edges, 36-float stride
    __shared__ float4 sCoefQ [DF * CO_STRIDE];   // (a,b,c,d), 33-f4 stride
    __shared__ float4 sCoarseQ[DF * CR_STRIDE];  // 8 octant edges, 12-float stride

    const int tid = threadIdx.x;
    const int ft = blockIdx.x & (D_SZ / DF - 1);     // 16 feature tiles
    const int rt = blockIdx.x >> 4;                  // 32 row tiles
    const int f0 = ft * DF;
    const int r0 = rt * RB;

    float* sLs = (float*)sLsQ;
    float* sCr = (float*)sCoarseQ;

    // stage tables: 64*32 = 2048 entries, 512 threads -> 4 each
    for (int t = tid; t < DF * NB; t += 512) {
        const int fl = t >> 5, kk = t & 31;
        sCoefQ[fl * CO_STRIDE + kk] = gCoef[(f0 + fl) * NB + kk];
        const float ls = gLs[(f0 + fl) * NB + kk];
        sLs[fl * (4 * LSQ_STRIDE) + kk] = ls;
        if ((kk & 3) == 3) sCr[fl * (4 * CR_STRIDE) + (kk >> 2)] = ls;
    }
    __syncthreads();

    const int lane   = tid & 63;
    const int waveId = tid >> 6;           // 0..7
    const int sub    = lane >> 4;          // row within wave-iter: 0..3
    const int g      = lane & 15;          // 16-lane group position
    const int flbase = g * 4;              // first of this lane's 4 features

    // per-lane coarse edges -> registers (loop-invariant)
    float C[8];
    {
        // coarse stored per feature; all 4 of this lane's features share... no:
        // coarse edges are PER FEATURE. Each of the 4 features has its own set.
    }
    float4 ca0 = sCoarseQ[(flbase + 0) * CR_STRIDE + 0];
    float4 ca1 = sCoarseQ[(flbase + 0) * CR_STRIDE + 1];
    float4 cb0 = sCoarseQ[(flbase + 1) * CR_STRIDE + 0];
    float4 cb1 = sCoarseQ[(flbase + 1) * CR_STRIDE + 1];
    float4 cc0 = sCoarseQ[(flbase + 2) * CR_STRIDE + 0];
    float4 cc1 = sCoarseQ[(flbase + 2) * CR_STRIDE + 1];
    float4 cd0 = sCoarseQ[(flbase + 3) * CR_STRIDE + 0];
    float4 cd1 = sCoarseQ[(flbase + 3) * CR_STRIDE + 1];

    const int rowsPerIter = 8 * 4;         // 8 waves x 4 rows
    #pragma unroll
    for (int it = 0; it < RB / rowsPerIter; ++it) {
        const int r = r0 + it * rowsPerIter + waveId * 4 + sub;
        const float4 x4 = inp[(r * D_SZ + f0) / 4 + g];
        const float xv[4] = {x4.x, x4.y, x4.z, x4.w};

        float4 o4;
        float* ov = (float*)&o4;
        float lsum = 0.0f;

        #pragma unroll
        for (int j = 0; j < 4; ++j) {
            const int fl = flbase + j;
            const float x = xv[j];
            const float4 q0 = (j == 0) ? ca0 : (j == 1) ? cb0 : (j == 2) ? cc0 : cd0;
            const float4 q1 = (j == 0) ? ca1 : (j == 1) ? cb1 : (j == 2) ? cc1 : cd1;
            const float Cv[8] = {q0.x, q0.y, q0.z, q0.w, q1.x, q1.y, q1.z, q1.w};

            int o = 0; float prevC = 0.0f;
            #pragma unroll
            for (int c = 0; c < 8; ++c) {
                const bool ge = x >= Cv[c];
                o += ge ? 1 : 0;
                prevC = ge ? Cv[c] : prevC;
            }
            // o in [0,7] (Cv[7] = 2.0 sentinel)
            const float4 fine = sLsQ[fl * LSQ_STRIDE + o];
            const int cnt = (x >= fine.x ? 1 : 0) + (x >= fine.y ? 1 : 0)
                          + (x >= fine.z ? 1 : 0);
            const float cwl = (cnt == 0) ? prevC
                            : (cnt == 1) ? fine.x
                            : (cnt == 2) ? fine.y : fine.z;
            const int pos = 4 * o + cnt;

            const float4 cf = sCoefQ[fl * CO_STRIDE + pos];
            const float s = x - cwl;
            float oo = ((cf.x * s + cf.y) * s + cf.z) * s + cf.w;
            ov[j] = fminf(fmaxf(oo, 0.0f), 1.0f);
            const float der = (3.0f * cf.x * s + 2.0f * cf.y) * s + cf.z;
            lsum += __logf(fabsf(der));
        }

        out[(r * D_SZ + f0) / 4 + g] = o4;

        // reduce across the 16-lane row group
        for (int mm = 8; mm >= 1; mm >>= 1) lsum += __shfl_xor(lsum, mm, 16);
        if (g == 0) atomicAdd(&lad[r], lsum);
    }
}

// ---------------------------------------------------------------------------
extern "C" void kernel_launch(void* const* d_in, const int* in_sizes, int n_in,
                              void* d_out, int out_size, void* d_ws, size_t ws_size,
                              hipStream_t stream)
{
    const float* inputs = (const float*)d_in[0];
    const float* uw     = (const float*)d_in[1];
    const float* uh     = (const float*)d_in[2];
    const float* udl    = (const float*)d_in[3];
    const float* udr    = (const float*)d_in[4];

    float* out = (float*)d_out;                        // B*D outputs
    float* lad = out + (size_t)B_SZ * D_SZ;            // B logabsdet sums

    float4* gCoef = (float4*)d_ws;                                        // D*32*16B
    float*  gLs   = (float*)((char*)d_ws + (size_t)D_SZ * NB * sizeof(float4));

    spline_params<<<D_SZ / 8, 256, 0, stream>>>(uw, uh, udl, udr, gCoef, gLs, lad);
    spline_eval<<<(D_SZ / DF) * (B_SZ / RB), 512, 0, stream>>>(
        (const float4*)inputs, gCoef, gLs, (float4*)out, lad);
}